// Round 3
// baseline (1292.123 us; speedup 1.0000x reference)
//
#include <hip/hip_runtime.h>

typedef _Float16 half8 __attribute__((ext_vector_type(8)));
typedef _Float16 half4 __attribute__((ext_vector_type(4)));
typedef float floatx4 __attribute__((ext_vector_type(4)));

// LDS column-group swizzle (8-elem granularity) so 16-lane fragment reads spread banks.
#define SWZ(r) ((((r) & 7) << 1) | (((r) >> 3) & 1))

__device__ __forceinline__ void gld16(const void* g, void* l) {
  __builtin_amdgcn_global_load_lds(
      (const __attribute__((address_space(1))) unsigned int*)g,
      (__attribute__((address_space(3))) unsigned int*)l, 16, 0, 0);
}

// ---------------- fp32 -> f16 convert (8 elems/thread) ----------------
__global__ void f2h(const float* __restrict__ s, _Float16* __restrict__ d, int n8) {
  int i = blockIdx.x * 256 + threadIdx.x;
  if (i >= n8) return;
  float4 a = ((const float4*)s)[2 * i];
  float4 b = ((const float4*)s)[2 * i + 1];
  half8 h;
  h[0] = (_Float16)a.x; h[1] = (_Float16)a.y; h[2] = (_Float16)a.z; h[3] = (_Float16)a.w;
  h[4] = (_Float16)b.x; h[5] = (_Float16)b.y; h[6] = (_Float16)b.z; h[7] = (_Float16)b.w;
  ((half8*)d)[i] = h;
}

__global__ void bias_concat(const float* __restrict__ bq, const float* __restrict__ bk,
                            const float* __restrict__ bv, float* __restrict__ dst) {
  int i = blockIdx.x * 256 + threadIdx.x;
  if (i < 4096) dst[i] = bq[i];
  else if (i < 5120) dst[i] = bk[i - 4096];
  else if (i < 6144) dst[i] = bv[i - 5120];
}

// ---------------- GEMM: C[m,n] = sum_k A[m,k]*B[n,k] (+bias[n]) ----------------
// A:[M][K] f16, B:[N][K] f16 row-major. 128x128 tile, BK=32, 4 waves 2x2, 16x16x32 MFMA.
template <typename OutT, bool HasBias>
__global__ __launch_bounds__(256) void gemm_bt(const _Float16* __restrict__ A,
                                               const _Float16* __restrict__ B,
                                               const float* __restrict__ bias,
                                               OutT* __restrict__ C, int M, int N, int K) {
  __shared__ _Float16 as[128 * 32];
  __shared__ _Float16 bs[128 * 32];
  const int tid = threadIdx.x;
  const int w = tid >> 6, lane = tid & 63;
  const int quad = lane >> 4, l16 = lane & 15;
  const int M0 = blockIdx.y * 128, N0 = blockIdx.x * 128;
  const int wm = (w >> 1) * 64, wn = (w & 1) * 64;

  floatx4 acc[4][4];
#pragma unroll
  for (int i = 0; i < 4; ++i)
#pragma unroll
    for (int j = 0; j < 4; ++j) acc[i][j] = (floatx4){0.f, 0.f, 0.f, 0.f};

  // staging: call c covers rows [c*64, c*64+64); thread -> (row, 8-col group)
  const int r0 = tid >> 2, g0 = tid & 3;
  const int r1 = r0 + 64;
  const int c0 = (g0 ^ ((r0 >> 1) & 3)) * 8;  // swizzled global col offset
  const int c1 = (g0 ^ ((r1 >> 1) & 3)) * 8;
  const _Float16* A0 = A + (size_t)(M0 + r0) * K + c0;
  const _Float16* A1 = A + (size_t)(M0 + r1) * K + c1;
  const _Float16* B0 = B + (size_t)(N0 + r0) * K + c0;
  const _Float16* B1 = B + (size_t)(N0 + r1) * K + c1;
  _Float16* asw = &as[w * 512];
  _Float16* bsw = &bs[w * 512];

  int aoff[4], boff[4];
#pragma unroll
  for (int mi = 0; mi < 4; ++mi) {
    int ra = wm + mi * 16 + l16;
    aoff[mi] = ra * 32 + ((quad ^ ((ra >> 1) & 3)) * 8);
    int rb = wn + mi * 16 + l16;
    boff[mi] = rb * 32 + ((quad ^ ((rb >> 1) & 3)) * 8);
  }

  for (int kk = 0; kk < K; kk += 32) {
    __syncthreads();
    gld16(A0 + kk, asw);
    gld16(A1 + kk, asw + 2048);
    gld16(B0 + kk, bsw);
    gld16(B1 + kk, bsw + 2048);
    __syncthreads();
    half8 af[4], bf[4];
#pragma unroll
    for (int i = 0; i < 4; ++i) af[i] = *(const half8*)&as[aoff[i]];
#pragma unroll
    for (int i = 0; i < 4; ++i) bf[i] = *(const half8*)&bs[boff[i]];
#pragma unroll
    for (int mi = 0; mi < 4; ++mi)
#pragma unroll
      for (int ni = 0; ni < 4; ++ni)
        acc[mi][ni] = __builtin_amdgcn_mfma_f32_16x16x32_f16(af[mi], bf[ni], acc[mi][ni], 0, 0, 0);
  }

#pragma unroll
  for (int mi = 0; mi < 4; ++mi)
#pragma unroll
    for (int ni = 0; ni < 4; ++ni) {
      int row = M0 + wm + mi * 16 + quad * 4;
      int col = N0 + wn + ni * 16 + l16;
      float bvv = HasBias ? bias[col] : 0.f;
#pragma unroll
      for (int r = 0; r < 4; ++r) {
        float v = acc[mi][ni][r] + bvv;
        C[(size_t)(row + r) * N + col] = (OutT)v;
      }
    }
}

// ---------------- RoPE for Q (scaled by 1/sqrt(HD)) and K ----------------
// qkv: [4096][6144] f16.  q_r: [B][32][2048][128], k_r: [B][8][2048][128]
__global__ void rope_qk(const _Float16* __restrict__ qkv, const float* __restrict__ cosb,
                        const float* __restrict__ sinb, _Float16* __restrict__ q_r,
                        _Float16* __restrict__ k_r) {
  int t = blockIdx.x * 256 + threadIdx.x;  // [0, 2*2048*40*64)
  int d = t & 63;
  int r = t >> 6;
  int hh = r % 40;
  int r2 = r / 40;
  int s = r2 & 2047;
  int b = r2 >> 11;
  size_t mrow = (size_t)(b * 2048 + s) * 6144;
  float c = cosb[s * 128 + d], sn = sinb[s * 128 + d];
  if (hh < 32) {
    size_t base = mrow + hh * 128 + d;
    float x1 = (float)qkv[base], x2 = (float)qkv[base + 64];
    const float sc = 0.08838834764831845f;  // 1/sqrt(128)
    float o1 = (x1 * c - x2 * sn) * sc;
    float o2 = (x2 * c + x1 * sn) * sc;
    size_t ob = ((size_t)((b * 32 + hh) * 2048 + s)) * 128 + d;
    q_r[ob] = (_Float16)o1;
    q_r[ob + 64] = (_Float16)o2;
  } else {
    int hk = hh - 32;
    size_t base = mrow + 4096 + hk * 128 + d;
    float x1 = (float)qkv[base], x2 = (float)qkv[base + 64];
    float o1 = x1 * c - x2 * sn;
    float o2 = x2 * c + x1 * sn;
    size_t ob = ((size_t)((b * 8 + hk) * 2048 + s)) * 128 + d;
    k_r[ob] = (_Float16)o1;
    k_r[ob + 64] = (_Float16)o2;
  }
}

// ---------------- V transpose: qkv v-part -> v_t[b][hv][d][s] ----------------
__global__ void v_transpose(const _Float16* __restrict__ qkv, _Float16* __restrict__ v_t) {
  __shared__ _Float16 tile[32][33];
  int st = blockIdx.x * 32, dt = blockIdx.y * 32, bh = blockIdx.z;
  int tx = threadIdx.x & 31, ty = threadIdx.x >> 5;  // ty 0..7
  int b = bh >> 3, hv = bh & 7;
#pragma unroll
  for (int j = 0; j < 4; ++j) {
    int s = st + ty + j * 8;
    tile[ty + j * 8][tx] = qkv[(size_t)(b * 2048 + s) * 6144 + 5120 + hv * 128 + dt + tx];
  }
  __syncthreads();
#pragma unroll
  for (int j = 0; j < 4; ++j)
    v_t[((size_t)bh * 128 + dt + ty + j * 8) * 2048 + st + tx] = tile[tx][ty + j * 8];
}

// ---------------- Flash attention (S^T formulation) ----------------
// Computes S^T = K·Q^T so the MFMA C-layout lands with q on l16: softmax is
// per-lane + 2 shuffles, P^T->LDS is vector b64 writes, PV B-frags are b128
// reads, O^T C-layout gives 4 consecutive d per lane for b64 global stores.
// q_r:[B][32][2048][128] (pre-scaled), k_r:[B][8][2048][128], v_t:[B][8][128][2048]
// att:[B*2048][4096] f16. Block = 64 q rows (4 waves x 16), K-tiles of 128 kv.
// LDS = K tile only (32 KB; P^T overlays it). V^T frags read direct from global (L2-hot).
__global__ __launch_bounds__(256, 3) void attn_kernel(const _Float16* __restrict__ q_r,
                                                      const _Float16* __restrict__ k_r,
                                                      const _Float16* __restrict__ v_t,
                                                      _Float16* __restrict__ att) {
  __shared__ __align__(16) _Float16 kt[128 * 128];  // K tile [kv][d]; later P^T as pt[q][kv]
  const int tid = threadIdx.x;
  const int w = tid >> 6, lane = tid & 63;
  const int quad = lane >> 4, l16 = lane & 15;
  const int qb = 31 - blockIdx.x;  // 64-row q block, heavy tiles dispatch first
  const int h = blockIdx.y, b = blockIdx.z;
  const int q0 = qb * 64;
  const _Float16* qh = q_r + ((size_t)(b * 32 + h) * 2048) * 128;
  const _Float16* kh = k_r + ((size_t)(b * 8 + (h >> 2)) * 2048) * 128;
  const _Float16* vh = v_t + ((size_t)(b * 8 + (h >> 2)) * 128) * 2048;

  const int myq = q0 + w * 16 + l16;  // this lane's q row (N dim of S^T)
  const int ql = w * 16 + l16;        // block-local q row for pt
  const int l8 = l16 & 7;

  // Q as B-operand fragments: B[n=q][k=d] — same register layout as A-operand.
  half8 bq[4];
#pragma unroll
  for (int kd = 0; kd < 4; ++kd)
    bq[kd] = *(const half8*)&qh[(size_t)myq * 128 + kd * 32 + quad * 8];

  floatx4 oacc[8];  // O^T: per lane q=myq, d = di*16 + quad*4 + r
#pragma unroll
  for (int di = 0; di < 8; ++di) oacc[di] = (floatx4){0.f, 0.f, 0.f, 0.f};
  float mrun = -1e30f, lrun = 0.f;

  const int srow0 = tid >> 4, sgrp = tid & 15;
  const int nkt = qb >> 1;  // last K-tile index (inclusive)

  for (int kti = 0; kti <= nkt; ++kti) {
    __syncthreads();  // everyone done with kt/pt from previous iteration
    const _Float16* kg = kh + (size_t)kti * 128 * 128;
#pragma unroll
    for (int c = 0; c < 8; ++c) {
      int row = srow0 + c * 16;
      int gc = (sgrp ^ SWZ(row)) * 8;
      gld16(kg + row * 128 + gc, &kt[w * 512 + c * 2048]);
    }
    // Prefetch V^T fragments for ks=0 (independent of LDS/barriers, L2-hot).
    const _Float16* vg = vh + kti * 128;
    half8 va[8], vb[8];
#pragma unroll
    for (int di = 0; di < 8; ++di)
      va[di] = *(const half8*)&vg[(size_t)(di * 16 + l16) * 2048 + quad * 8];
    __syncthreads();

    // ---- S^T = K·Q^T : A = K (M=kv=128), B = Q (N=q=16), K-dim = d=128 ----
    floatx4 sacc[8];  // per lane: q=myq, kv = kti*128 + ni*16 + quad*4 + r
#pragma unroll
    for (int ni = 0; ni < 8; ++ni) sacc[ni] = (floatx4){0.f, 0.f, 0.f, 0.f};
#pragma unroll
    for (int ni = 0; ni < 8; ++ni) {
      int rowk = ni * 16 + l16;
#pragma unroll
      for (int kd = 0; kd < 4; ++kd) {
        int grp = (kd * 4 + quad) ^ SWZ(rowk);
        half8 ka = *(const half8*)&kt[rowk * 128 + grp * 8];
        sacc[ni] = __builtin_amdgcn_mfma_f32_16x16x32_f16(ka, bq[kd], sacc[ni], 0, 0, 0);
      }
    }

    if (kti == nkt) {  // causal mask on the diagonal tile: kv > q
#pragma unroll
      for (int ni = 0; ni < 8; ++ni) {
        int kvbase = kti * 128 + ni * 16 + quad * 4;
#pragma unroll
        for (int r = 0; r < 4; ++r)
          if (kvbase + r > myq) sacc[ni][r] = -1e30f;
      }
    }

    // ---- online softmax: per lane ONE q row; reduce in-lane then across quads ----
    float tm = -1e30f;
#pragma unroll
    for (int ni = 0; ni < 8; ++ni)
#pragma unroll
      for (int r = 0; r < 4; ++r) tm = fmaxf(tm, sacc[ni][r]);
    tm = fmaxf(tm, __shfl_xor(tm, 16));
    tm = fmaxf(tm, __shfl_xor(tm, 32));
    float nm = fmaxf(mrun, tm);
    float al = __expf(mrun - nm);
    mrun = nm;
    float ts = 0.f;
#pragma unroll
    for (int ni = 0; ni < 8; ++ni)
#pragma unroll
      for (int r = 0; r < 4; ++r) {
        float pv = __expf(sacc[ni][r] - nm);
        sacc[ni][r] = pv;
        ts += pv;
      }
    ts += __shfl_xor(ts, 16);
    ts += __shfl_xor(ts, 32);
    lrun = lrun * al + ts;
#pragma unroll
    for (int di = 0; di < 8; ++di) oacc[di] *= al;

    __syncthreads();  // all waves done reading kt A-frags before P^T overlays it
    // pt[q][kv]: addr = q*128 + ((kv>>3) ^ (q&7))*8 + (kv&7). Conflict-free b64
    // writes (4 consecutive kv per lane) and b128 reads (8 consecutive kv).
#pragma unroll
    for (int ni = 0; ni < 8; ++ni) {
      half4 p4;
#pragma unroll
      for (int r = 0; r < 4; ++r) p4[r] = (_Float16)sacc[ni][r];
      int grp = (ni * 2 + (quad >> 1)) ^ l8;
      *(half4*)&kt[ql * 128 + grp * 8 + (quad & 1) * 4] = p4;
    }
    // No barrier: each wave reads back only its own q rows.

    // ---- O^T += V^T · P^T : A = V^T (M=d=128), B = P^T (N=q=16), K-dim = kv ----
    // ks-group V prefetch alternates va/vb one group ahead.
#pragma unroll
    for (int di = 0; di < 8; ++di)
      vb[di] = *(const half8*)&vg[(size_t)(di * 16 + l16) * 2048 + 32 + quad * 8];
    {
      half8 pb = *(const half8*)&kt[ql * 128 + ((0 * 4 + quad) ^ l8) * 8];
#pragma unroll
      for (int di = 0; di < 8; ++di)
        oacc[di] = __builtin_amdgcn_mfma_f32_16x16x32_f16(va[di], pb, oacc[di], 0, 0, 0);
    }
#pragma unroll
    for (int di = 0; di < 8; ++di)
      va[di] = *(const half8*)&vg[(size_t)(di * 16 + l16) * 2048 + 64 + quad * 8];
    {
      half8 pb = *(const half8*)&kt[ql * 128 + ((1 * 4 + quad) ^ l8) * 8];
#pragma unroll
      for (int di = 0; di < 8; ++di)
        oacc[di] = __builtin_amdgcn_mfma_f32_16x16x32_f16(vb[di], pb, oacc[di], 0, 0, 0);
    }
#pragma unroll
    for (int di = 0; di < 8; ++di)
      vb[di] = *(const half8*)&vg[(size_t)(di * 16 + l16) * 2048 + 96 + quad * 8];
    {
      half8 pb = *(const half8*)&kt[ql * 128 + ((2 * 4 + quad) ^ l8) * 8];
#pragma unroll
      for (int di = 0; di < 8; ++di)
        oacc[di] = __builtin_amdgcn_mfma_f32_16x16x32_f16(va[di], pb, oacc[di], 0, 0, 0);
    }
    {
      half8 pb = *(const half8*)&kt[ql * 128 + ((3 * 4 + quad) ^ l8) * 8];
#pragma unroll
      for (int di = 0; di < 8; ++di)
        oacc[di] = __builtin_amdgcn_mfma_f32_16x16x32_f16(vb[di], pb, oacc[di], 0, 0, 0);
    }
  }

  // ---- epilogue: normalize and store O (4 consecutive d per lane -> b64 stores) ----
  float inv = 1.f / lrun;
#pragma unroll
  for (int di = 0; di < 8; ++di) {
    half4 o4;
#pragma unroll
    for (int r = 0; r < 4; ++r) o4[r] = (_Float16)(oacc[di][r] * inv);
    *(half4*)&att[((size_t)b * 2048 + myq) * 4096 + h * 128 + di * 16 + quad * 4] = o4;
  }
}

extern "C" void kernel_launch(void* const* d_in, const int* in_sizes, int n_in, void* d_out,
                              int out_size, void* d_ws, size_t ws_size, hipStream_t stream) {
  const float* x = (const float*)d_in[0];
  const float* cosb = (const float*)d_in[1];
  const float* sinb = (const float*)d_in[2];
  const float* Wq = (const float*)d_in[3];
  const float* bq = (const float*)d_in[4];
  const float* Wk = (const float*)d_in[5];
  const float* bk = (const float*)d_in[6];
  const float* Wv = (const float*)d_in[7];
  const float* bv = (const float*)d_in[8];
  const float* Wo = (const float*)d_in[9];
  float* out = (float*)d_out;

  char* p = (char*)d_ws;
  _Float16* xb = (_Float16*)p;   p += (size_t)4096 * 4096 * 2;
  _Float16* wqkv = (_Float16*)p; p += (size_t)6144 * 4096 * 2;
  _Float16* wo_b = (_Float16*)p; p += (size_t)4096 * 4096 * 2;
  _Float16* qkv = (_Float16*)p;  p += (size_t)4096 * 6144 * 2;
  _Float16* q_r = (_Float16*)p;  p += (size_t)2 * 32 * 2048 * 128 * 2;
  _Float16* k_r = (_Float16*)p;  p += (size_t)2 * 8 * 2048 * 128 * 2;
  _Float16* v_t = (_Float16*)p;  p += (size_t)2 * 8 * 128 * 2048 * 2;
  _Float16* att = (_Float16*)p;  p += (size_t)4096 * 4096 * 2;
  float* biasc = (float*)p;      p += 6144 * 4;

  f2h<<<8192, 256, 0, stream>>>(x, xb, 2097152);
  f2h<<<8192, 256, 0, stream>>>(Wq, wqkv, 2097152);
  f2h<<<2048, 256, 0, stream>>>(Wk, wqkv + (size_t)4096 * 4096, 524288);
  f2h<<<2048, 256, 0, stream>>>(Wv, wqkv + (size_t)5120 * 4096, 524288);
  f2h<<<8192, 256, 0, stream>>>(Wo, wo_b, 2097152);
  bias_concat<<<24, 256, 0, stream>>>(bq, bk, bv, biasc);

  gemm_bt<_Float16, true><<<dim3(48, 32), 256, 0, stream>>>(xb, wqkv, biasc, qkv, 4096, 6144, 4096);
  rope_qk<<<40960, 256, 0, stream>>>(qkv, cosb, sinb, q_r, k_r);
  v_transpose<<<dim3(64, 4, 16), 256, 0, stream>>>(qkv, v_t);
  attn_kernel<<<dim3(32, 32, 2), 256, 0, stream>>>(q_r, k_r, v_t, att);
  gemm_bt<float, false><<<dim3(32, 32), 256, 0, stream>>>(att, wo_b, nullptr, out, 4096, 4096, 4096);
}

// Round 4
// 951.937 us; speedup vs baseline: 1.3574x; 1.3574x over previous
//
#include <hip/hip_runtime.h>

typedef _Float16 half8 __attribute__((ext_vector_type(8)));
typedef _Float16 half4 __attribute__((ext_vector_type(4)));
typedef float floatx4 __attribute__((ext_vector_type(4)));
typedef float floatx16 __attribute__((ext_vector_type(16)));

// LDS column-group swizzle (8-elem granularity) so fragment reads spread banks.
#define SWZ(r) ((((r) & 7) << 1) | (((r) >> 3) & 1))

__device__ __forceinline__ void gld16(const void* g, void* l) {
  __builtin_amdgcn_global_load_lds(
      (const __attribute__((address_space(1))) unsigned int*)g,
      (__attribute__((address_space(3))) unsigned int*)l, 16, 0, 0);
}

// ---------------- fp32 -> f16 convert (8 elems/thread) ----------------
__global__ void f2h(const float* __restrict__ s, _Float16* __restrict__ d, int n8) {
  int i = blockIdx.x * 256 + threadIdx.x;
  if (i >= n8) return;
  float4 a = ((const float4*)s)[2 * i];
  float4 b = ((const float4*)s)[2 * i + 1];
  half8 h;
  h[0] = (_Float16)a.x; h[1] = (_Float16)a.y; h[2] = (_Float16)a.z; h[3] = (_Float16)a.w;
  h[4] = (_Float16)b.x; h[5] = (_Float16)b.y; h[6] = (_Float16)b.z; h[7] = (_Float16)b.w;
  ((half8*)d)[i] = h;
}

__global__ void bias_concat(const float* __restrict__ bq, const float* __restrict__ bk,
                            const float* __restrict__ bv, float* __restrict__ dst) {
  int i = blockIdx.x * 256 + threadIdx.x;
  if (i < 4096) dst[i] = bq[i];
  else if (i < 5120) dst[i] = bk[i - 4096];
  else if (i < 6144) dst[i] = bv[i - 5120];
}

// ---------------- GEMM: C[m,n] = sum_k A[m,k]*B[n,k] (+bias[n]) ----------------
template <typename OutT, bool HasBias>
__global__ __launch_bounds__(256) void gemm_bt(const _Float16* __restrict__ A,
                                               const _Float16* __restrict__ B,
                                               const float* __restrict__ bias,
                                               OutT* __restrict__ C, int M, int N, int K) {
  __shared__ _Float16 as[128 * 32];
  __shared__ _Float16 bs[128 * 32];
  const int tid = threadIdx.x;
  const int w = tid >> 6, lane = tid & 63;
  const int quad = lane >> 4, l16 = lane & 15;
  const int M0 = blockIdx.y * 128, N0 = blockIdx.x * 128;
  const int wm = (w >> 1) * 64, wn = (w & 1) * 64;

  floatx4 acc[4][4];
#pragma unroll
  for (int i = 0; i < 4; ++i)
#pragma unroll
    for (int j = 0; j < 4; ++j) acc[i][j] = (floatx4){0.f, 0.f, 0.f, 0.f};

  const int r0 = tid >> 2, g0 = tid & 3;
  const int r1 = r0 + 64;
  const int c0 = (g0 ^ ((r0 >> 1) & 3)) * 8;
  const int c1 = (g0 ^ ((r1 >> 1) & 3)) * 8;
  const _Float16* A0 = A + (size_t)(M0 + r0) * K + c0;
  const _Float16* A1 = A + (size_t)(M0 + r1) * K + c1;
  const _Float16* B0 = B + (size_t)(N0 + r0) * K + c0;
  const _Float16* B1 = B + (size_t)(N0 + r1) * K + c1;
  _Float16* asw = &as[w * 512];
  _Float16* bsw = &bs[w * 512];

  int aoff[4], boff[4];
#pragma unroll
  for (int mi = 0; mi < 4; ++mi) {
    int ra = wm + mi * 16 + l16;
    aoff[mi] = ra * 32 + ((quad ^ ((ra >> 1) & 3)) * 8);
    int rb = wn + mi * 16 + l16;
    boff[mi] = rb * 32 + ((quad ^ ((rb >> 1) & 3)) * 8);
  }

  for (int kk = 0; kk < K; kk += 32) {
    __syncthreads();
    gld16(A0 + kk, asw);
    gld16(A1 + kk, asw + 2048);
    gld16(B0 + kk, bsw);
    gld16(B1 + kk, bsw + 2048);
    __syncthreads();
    half8 af[4], bf[4];
#pragma unroll
    for (int i = 0; i < 4; ++i) af[i] = *(const half8*)&as[aoff[i]];
#pragma unroll
    for (int i = 0; i < 4; ++i) bf[i] = *(const half8*)&bs[boff[i]];
#pragma unroll
    for (int mi = 0; mi < 4; ++mi)
#pragma unroll
      for (int ni = 0; ni < 4; ++ni)
        acc[mi][ni] = __builtin_amdgcn_mfma_f32_16x16x32_f16(af[mi], bf[ni], acc[mi][ni], 0, 0, 0);
  }

#pragma unroll
  for (int mi = 0; mi < 4; ++mi)
#pragma unroll
    for (int ni = 0; ni < 4; ++ni) {
      int row = M0 + wm + mi * 16 + quad * 4;
      int col = N0 + wn + ni * 16 + l16;
      float bvv = HasBias ? bias[col] : 0.f;
#pragma unroll
      for (int r = 0; r < 4; ++r) {
        float v = acc[mi][ni][r] + bvv;
        C[(size_t)(row + r) * N + col] = (OutT)v;
      }
    }
}

// ---------------- RoPE for Q (scaled by log2e/sqrt(HD)) and K ----------------
// Q carries the softmax scale AND log2(e) so attention can use native exp2.
__global__ void rope_qk(const _Float16* __restrict__ qkv, const float* __restrict__ cosb,
                        const float* __restrict__ sinb, _Float16* __restrict__ q_r,
                        _Float16* __restrict__ k_r) {
  int t = blockIdx.x * 256 + threadIdx.x;
  int d = t & 63;
  int r = t >> 6;
  int hh = r % 40;
  int r2 = r / 40;
  int s = r2 & 2047;
  int b = r2 >> 11;
  size_t mrow = (size_t)(b * 2048 + s) * 6144;
  float c = cosb[s * 128 + d], sn = sinb[s * 128 + d];
  if (hh < 32) {
    size_t base = mrow + hh * 128 + d;
    float x1 = (float)qkv[base], x2 = (float)qkv[base + 64];
    const float sc = 0.12751744737079736f;  // log2(e)/sqrt(128)
    float o1 = (x1 * c - x2 * sn) * sc;
    float o2 = (x2 * c + x1 * sn) * sc;
    size_t ob = ((size_t)((b * 32 + hh) * 2048 + s)) * 128 + d;
    q_r[ob] = (_Float16)o1;
    q_r[ob + 64] = (_Float16)o2;
  } else {
    int hk = hh - 32;
    size_t base = mrow + 4096 + hk * 128 + d;
    float x1 = (float)qkv[base], x2 = (float)qkv[base + 64];
    float o1 = x1 * c - x2 * sn;
    float o2 = x2 * c + x1 * sn;
    size_t ob = ((size_t)((b * 8 + hk) * 2048 + s)) * 128 + d;
    k_r[ob] = (_Float16)o1;
    k_r[ob + 64] = (_Float16)o2;
  }
}

// ---------------- V transpose: qkv v-part -> v_t[b][hv][d][s] ----------------
__global__ void v_transpose(const _Float16* __restrict__ qkv, _Float16* __restrict__ v_t) {
  __shared__ _Float16 tile[32][33];
  int st = blockIdx.x * 32, dt = blockIdx.y * 32, bh = blockIdx.z;
  int tx = threadIdx.x & 31, ty = threadIdx.x >> 5;
  int b = bh >> 3, hv = bh & 7;
#pragma unroll
  for (int j = 0; j < 4; ++j) {
    int s = st + ty + j * 8;
    tile[ty + j * 8][tx] = qkv[(size_t)(b * 2048 + s) * 6144 + 5120 + hv * 128 + dt + tx];
  }
  __syncthreads();
#pragma unroll
  for (int j = 0; j < 4; ++j)
    v_t[((size_t)bh * 128 + dt + ty + j * 8) * 2048 + st + tx] = tile[tx][ty + j * 8];
}

// ---------------- Flash attention: S^T form, 32x32x16 MFMA ----------------
// q-block 128 (4 waves x 32 q on lane&31), kv-tile 128. K and V^T in LDS
// (staged once per block per tile); P^T overlays the K tile after a barrier.
// 32x32 halves LDS A-frag bytes per FLOP vs 16x16 (the measured bottleneck).
// C-layout (m74/m101): col = lane&31 (=q), row = (reg&3) + 8*(reg>>2) + 4*(lane>>5).
// A/B frag: m/n = lane&31, k = (lane>>5)*8 + j.
__global__ __launch_bounds__(256, 2) void attn_kernel(const _Float16* __restrict__ q_r,
                                                      const _Float16* __restrict__ k_r,
                                                      const _Float16* __restrict__ v_t,
                                                      _Float16* __restrict__ att) {
  __shared__ __align__(16) _Float16 kt[128 * 128];  // K tile [kv][d]; later P^T [q][kv]
  __shared__ __align__(16) _Float16 vt[128 * 128];  // V^T tile [d][kv]
  const int tid = threadIdx.x;
  const int w = tid >> 6, lane = tid & 63;
  const int l32 = lane & 31, hi = lane >> 5;
  const int qb = 15 - blockIdx.x;  // heavy q-tiles dispatch first
  const int h = blockIdx.y, b = blockIdx.z;
  const int q0 = qb * 128;
  const _Float16* qh = q_r + ((size_t)(b * 32 + h) * 2048) * 128;
  const _Float16* kh = k_r + ((size_t)(b * 8 + (h >> 2)) * 2048) * 128;
  const _Float16* vh = v_t + ((size_t)(b * 8 + (h >> 2)) * 128) * 2048;

  const int ql = w * 32 + l32;  // block-local q row
  const int myq = q0 + ql;
  const int swq = SWZ(ql);
  const int swl = SWZ(l32);  // == SWZ(ni*32 + l32) for any ni (bit3 of row = bit3 of l32)

  // Q as B-operand: n = l32 (q), k = hi*8 + j within each 16-wide kd chunk.
  half8 bq[8];
#pragma unroll
  for (int kd = 0; kd < 8; ++kd)
    bq[kd] = *(const half8*)&qh[(size_t)myq * 128 + kd * 16 + hi * 8];

  floatx16 oacc[4];  // O^T: q = l32, d = di*32 + (reg&3) + 8*(reg>>2) + 4*hi
#pragma unroll
  for (int di = 0; di < 4; ++di)
#pragma unroll
    for (int j = 0; j < 16; ++j) oacc[di][j] = 0.f;
  float mrun = -1e30f, lrun = 0.f;

  const int srow0 = tid >> 4, sgrp = tid & 15;

  for (int kti = 0; kti <= qb; ++kti) {
    __syncthreads();  // prev iter's P/V reads complete before restaging
    const _Float16* kg = kh + (size_t)kti * 128 * 128;
#pragma unroll
    for (int c = 0; c < 8; ++c) {
      int row = srow0 + c * 16;
      int gc = (sgrp ^ SWZ(row)) * 8;
      gld16(kg + row * 128 + gc, &kt[w * 512 + c * 2048]);
    }
#pragma unroll
    for (int c = 0; c < 8; ++c) {
      int row = srow0 + c * 16;
      int gc = (sgrp ^ SWZ(row)) * 8;
      gld16(vh + (size_t)row * 2048 + kti * 128 + gc, &vt[w * 512 + c * 2048]);
    }
    __syncthreads();  // K,V published

    // ---- S^T = K·Q^T : A = K rows (m=kv), B = Q (n=q), k-dim = d ----
    floatx16 sacc[4];
#pragma unroll
    for (int ni = 0; ni < 4; ++ni)
#pragma unroll
      for (int j = 0; j < 16; ++j) sacc[ni][j] = 0.f;
#pragma unroll
    for (int ni = 0; ni < 4; ++ni) {
      int rb = (ni * 32 + l32) * 128;
#pragma unroll
      for (int kd = 0; kd < 8; ++kd) {
        half8 ka = *(const half8*)&kt[rb + (((kd * 2 + hi) ^ swl) * 8)];
        sacc[ni] = __builtin_amdgcn_mfma_f32_32x32x16_f16(ka, bq[kd], sacc[ni], 0, 0, 0);
      }
    }

    if (kti == qb) {  // causal mask on diagonal tile: kv > q
#pragma unroll
      for (int ni = 0; ni < 4; ++ni)
#pragma unroll
        for (int g = 0; g < 4; ++g) {
          int kvb = kti * 128 + ni * 32 + g * 8 + hi * 4;
#pragma unroll
          for (int t = 0; t < 4; ++t)
            if (kvb + t > myq) sacc[ni][g * 4 + t] = -1e30f;
        }
    }

    // ---- online softmax (exp2 domain), one q row per lane ----
    float tm = -1e30f;
#pragma unroll
    for (int ni = 0; ni < 4; ++ni)
#pragma unroll
      for (int j = 0; j < 16; ++j) tm = fmaxf(tm, sacc[ni][j]);
    tm = fmaxf(tm, __shfl_xor(tm, 32));
    float nm = fmaxf(mrun, tm);
    float al = exp2f(mrun - nm);
    mrun = nm;
    float ts = 0.f;
#pragma unroll
    for (int ni = 0; ni < 4; ++ni)
#pragma unroll
      for (int j = 0; j < 16; ++j) {
        float p = exp2f(sacc[ni][j] - nm);
        sacc[ni][j] = p;
        ts += p;
      }
    ts += __shfl_xor(ts, 32);
    lrun = lrun * al + ts;
#pragma unroll
    for (int di = 0; di < 4; ++di)
#pragma unroll
      for (int j = 0; j < 16; ++j) oacc[di][j] *= al;

    __syncthreads();  // all waves done reading kt before P^T overlays it

    // P^T[q][kv]: phys group = (kv>>3) ^ SWZ(q), half-group offset hi*4.
#pragma unroll
    for (int ni = 0; ni < 4; ++ni)
#pragma unroll
      for (int g = 0; g < 4; ++g) {
        half4 p4;
#pragma unroll
        for (int t = 0; t < 4; ++t) p4[t] = (_Float16)sacc[ni][g * 4 + t];
        *(half4*)&kt[ql * 128 + (((ni * 4 + g) ^ swq) * 8) + hi * 4] = p4;
      }
    // No barrier: each wave reads back only its own 32 q rows (within-wave dep).

    // ---- O^T += V^T · P^T : A = V^T rows (m=d), B = P^T (n=q), k-dim = kv ----
#pragma unroll
    for (int ks = 0; ks < 8; ++ks) {
      half8 pb = *(const half8*)&kt[ql * 128 + (((ks * 2 + hi) ^ swq) * 8)];
#pragma unroll
      for (int di = 0; di < 4; ++di) {
        int rv = (di * 32 + l32) * 128;
        half8 va = *(const half8*)&vt[rv + (((ks * 2 + hi) ^ swl) * 8)];
        oacc[di] = __builtin_amdgcn_mfma_f32_32x32x16_f16(va, pb, oacc[di], 0, 0, 0);
      }
    }
  }

  // ---- epilogue: normalize, store O (half4 per (di,g), d contiguous) ----
  float inv = 1.f / lrun;
  _Float16* ob = att + ((size_t)b * 2048 + myq) * 4096 + h * 128;
#pragma unroll
  for (int di = 0; di < 4; ++di)
#pragma unroll
    for (int g = 0; g < 4; ++g) {
      half4 o4;
#pragma unroll
      for (int t = 0; t < 4; ++t) o4[t] = (_Float16)(oacc[di][g * 4 + t] * inv);
      *(half4*)&ob[di * 32 + g * 8 + hi * 4] = o4;
    }
}

extern "C" void kernel_launch(void* const* d_in, const int* in_sizes, int n_in, void* d_out,
                              int out_size, void* d_ws, size_t ws_size, hipStream_t stream) {
  const float* x = (const float*)d_in[0];
  const float* cosb = (const float*)d_in[1];
  const float* sinb = (const float*)d_in[2];
  const float* Wq = (const float*)d_in[3];
  const float* bq = (const float*)d_in[4];
  const float* Wk = (const float*)d_in[5];
  const float* bk = (const float*)d_in[6];
  const float* Wv = (const float*)d_in[7];
  const float* bv = (const float*)d_in[8];
  const float* Wo = (const float*)d_in[9];
  float* out = (float*)d_out;

  char* p = (char*)d_ws;
  _Float16* xb = (_Float16*)p;   p += (size_t)4096 * 4096 * 2;
  _Float16* wqkv = (_Float16*)p; p += (size_t)6144 * 4096 * 2;
  _Float16* wo_b = (_Float16*)p; p += (size_t)4096 * 4096 * 2;
  _Float16* qkv = (_Float16*)p;  p += (size_t)4096 * 6144 * 2;
  _Float16* q_r = (_Float16*)p;  p += (size_t)2 * 32 * 2048 * 128 * 2;
  _Float16* k_r = (_Float16*)p;  p += (size_t)2 * 8 * 2048 * 128 * 2;
  _Float16* v_t = (_Float16*)p;  p += (size_t)2 * 8 * 128 * 2048 * 2;
  _Float16* att = (_Float16*)p;  p += (size_t)4096 * 4096 * 2;
  float* biasc = (float*)p;      p += 6144 * 4;

  f2h<<<8192, 256, 0, stream>>>(x, xb, 2097152);
  f2h<<<8192, 256, 0, stream>>>(Wq, wqkv, 2097152);
  f2h<<<2048, 256, 0, stream>>>(Wk, wqkv + (size_t)4096 * 4096, 524288);
  f2h<<<2048, 256, 0, stream>>>(Wv, wqkv + (size_t)5120 * 4096, 524288);
  f2h<<<8192, 256, 0, stream>>>(Wo, wo_b, 2097152);
  bias_concat<<<24, 256, 0, stream>>>(bq, bk, bv, biasc);

  gemm_bt<_Float16, true><<<dim3(48, 32), 256, 0, stream>>>(xb, wqkv, biasc, qkv, 4096, 6144, 4096);
  rope_qk<<<40960, 256, 0, stream>>>(qkv, cosb, sinb, q_r, k_r);
  v_transpose<<<dim3(64, 4, 16), 256, 0, stream>>>(qkv, v_t);
  attn_kernel<<<dim3(16, 32, 2), 256, 0, stream>>>(q_r, k_r, v_t, att);
  gemm_bt<float, false><<<dim3(32, 32), 256, 0, stream>>>(att, wo_b, nullptr, out, 4096, 4096, 4096);
}

// Round 5
// 896.319 us; speedup vs baseline: 1.4416x; 1.0621x over previous
//
#include <hip/hip_runtime.h>

typedef _Float16 half8 __attribute__((ext_vector_type(8)));
typedef _Float16 half4 __attribute__((ext_vector_type(4)));
typedef float floatx4 __attribute__((ext_vector_type(4)));
typedef float floatx16 __attribute__((ext_vector_type(16)));

// LDS column-group swizzle (8-elem granularity) so fragment reads spread banks.
#define SWZ(r) ((((r) & 7) << 1) | (((r) >> 3) & 1))

__device__ __forceinline__ void gld16(const void* g, void* l) {
  __builtin_amdgcn_global_load_lds(
      (const __attribute__((address_space(1))) unsigned int*)g,
      (__attribute__((address_space(3))) unsigned int*)l, 16, 0, 0);
}

// ---------------- fused fp32 -> f16 converts + bias concat (1 dispatch) ----------------
// segments (in 8-elem groups): x 2097152 | Wq 2097152 | Wk 524288 | Wv 524288 | Wo 2097152
// then 6144 bias floats.
__global__ void convert_all(const float* __restrict__ x, const float* __restrict__ Wq,
                            const float* __restrict__ Wk, const float* __restrict__ Wv,
                            const float* __restrict__ Wo, const float* __restrict__ bq,
                            const float* __restrict__ bk, const float* __restrict__ bv,
                            _Float16* __restrict__ xb, _Float16* __restrict__ wqkv,
                            _Float16* __restrict__ wo_b, float* __restrict__ biasc) {
  long i = (long)blockIdx.x * 256 + threadIdx.x;
  const long N0 = 2097152, N1 = N0 + 2097152, N2 = N1 + 524288, N3 = N2 + 524288,
             N4 = N3 + 2097152;
  const float* s;
  _Float16* d;
  long j;
  if (i < N0) { s = x; d = xb; j = i; }
  else if (i < N1) { s = Wq; d = wqkv; j = i - N0; }
  else if (i < N2) { s = Wk; d = wqkv + (size_t)4096 * 4096; j = i - N1; }
  else if (i < N3) { s = Wv; d = wqkv + (size_t)5120 * 4096; j = i - N2; }
  else if (i < N4) { s = Wo; d = wo_b; j = i - N3; }
  else {
    long k = i - N4;
    if (k < 4096) biasc[k] = bq[k];
    else if (k < 5120) biasc[k] = bk[k - 4096];
    else if (k < 6144) biasc[k] = bv[k - 5120];
    return;
  }
  float4 a = ((const float4*)s)[2 * j];
  float4 b2 = ((const float4*)s)[2 * j + 1];
  half8 h;
  h[0] = (_Float16)a.x; h[1] = (_Float16)a.y; h[2] = (_Float16)a.z; h[3] = (_Float16)a.w;
  h[4] = (_Float16)b2.x; h[5] = (_Float16)b2.y; h[6] = (_Float16)b2.z; h[7] = (_Float16)b2.w;
  ((half8*)d)[j] = h;
}

// ---------------- GEMM: C[m,n] = sum_k A[m,k]*B[n,k] (+bias[n]) ----------------
// A:[M][K], B:[N][K] f16. 128x128 tile, BK=64 (half the barrier drains vs BK=32;
// BK=128 is the known m132 occupancy cliff). 4 waves 2x2, 16x16x32 MFMA.
// LDS [row][64] with phys group = logical_group ^ (row&7): staging stays a
// wave-uniform-base DMA, frag b128 reads are 2-way (free) bank aliased.
template <typename OutT, bool HasBias>
__global__ __launch_bounds__(256) void gemm_bt(const _Float16* __restrict__ A,
                                               const _Float16* __restrict__ B,
                                               const float* __restrict__ bias,
                                               OutT* __restrict__ C, int M, int N, int K) {
  __shared__ _Float16 as[128 * 64];
  __shared__ _Float16 bs[128 * 64];
  const int tid = threadIdx.x;
  const int w = tid >> 6, lane = tid & 63;
  const int quad = lane >> 4, l16 = lane & 15;
  const int M0 = blockIdx.y * 128, N0 = blockIdx.x * 128;
  const int wm = (w >> 1) * 64, wn = (w & 1) * 64;

  floatx4 acc[4][4];
#pragma unroll
  for (int i = 0; i < 4; ++i)
#pragma unroll
    for (int j = 0; j < 4; ++j) acc[i][j] = (floatx4){0.f, 0.f, 0.f, 0.f};

  // staging: call c covers rows [c*32, c*32+32); thread -> row=c*32+(tid>>3), grp=tid&7
  const int sr = tid >> 3, g0 = tid & 7;
  const int csw = (g0 ^ (sr & 7)) * 8;  // swizzled global col offset (c*32 preserves row&7)
  const _Float16* Ag[4];
  const _Float16* Bg[4];
  _Float16* asd[4];
  _Float16* bsd[4];
#pragma unroll
  for (int c = 0; c < 4; ++c) {
    Ag[c] = A + (size_t)(M0 + c * 32 + sr) * K + csw;
    Bg[c] = B + (size_t)(N0 + c * 32 + sr) * K + csw;
    asd[c] = &as[(c * 32 + w * 8) * 64];  // wave-uniform base; lane scatters +lane*16B
    bsd[c] = &bs[(c * 32 + w * 8) * 64];
  }

  int aoff[4][2], boff[4][2];
#pragma unroll
  for (int mi = 0; mi < 4; ++mi)
#pragma unroll
    for (int kd = 0; kd < 2; ++kd) {
      int ra = wm + mi * 16 + l16;
      aoff[mi][kd] = ra * 64 + (((kd * 4 + quad) ^ (ra & 7)) * 8);
      int rb = wn + mi * 16 + l16;
      boff[mi][kd] = rb * 64 + (((kd * 4 + quad) ^ (rb & 7)) * 8);
    }

  for (int kk = 0; kk < K; kk += 64) {
    __syncthreads();
#pragma unroll
    for (int c = 0; c < 4; ++c) gld16(Ag[c] + kk, asd[c]);
#pragma unroll
    for (int c = 0; c < 4; ++c) gld16(Bg[c] + kk, bsd[c]);
    __syncthreads();
#pragma unroll
    for (int kd = 0; kd < 2; ++kd) {
      half8 af[4], bf[4];
#pragma unroll
      for (int i = 0; i < 4; ++i) af[i] = *(const half8*)&as[aoff[i][kd]];
#pragma unroll
      for (int i = 0; i < 4; ++i) bf[i] = *(const half8*)&bs[boff[i][kd]];
#pragma unroll
      for (int mi = 0; mi < 4; ++mi)
#pragma unroll
        for (int ni = 0; ni < 4; ++ni)
          acc[mi][ni] = __builtin_amdgcn_mfma_f32_16x16x32_f16(af[mi], bf[ni], acc[mi][ni], 0, 0, 0);
    }
  }

#pragma unroll
  for (int mi = 0; mi < 4; ++mi)
#pragma unroll
    for (int ni = 0; ni < 4; ++ni) {
      int row = M0 + wm + mi * 16 + quad * 4;
      int col = N0 + wn + ni * 16 + l16;
      float bvv = HasBias ? bias[col] : 0.f;
#pragma unroll
      for (int r = 0; r < 4; ++r) {
        float v = acc[mi][ni][r] + bvv;
        C[(size_t)(row + r) * N + col] = (OutT)v;
      }
    }
}

// ---------------- RoPE for Q (scaled by log2e/sqrt(HD)) and K ----------------
__global__ void rope_qk(const _Float16* __restrict__ qkv, const float* __restrict__ cosb,
                        const float* __restrict__ sinb, _Float16* __restrict__ q_r,
                        _Float16* __restrict__ k_r) {
  int t = blockIdx.x * 256 + threadIdx.x;
  int d = t & 63;
  int r = t >> 6;
  int hh = r % 40;
  int r2 = r / 40;
  int s = r2 & 2047;
  int b = r2 >> 11;
  size_t mrow = (size_t)(b * 2048 + s) * 6144;
  float c = cosb[s * 128 + d], sn = sinb[s * 128 + d];
  if (hh < 32) {
    size_t base = mrow + hh * 128 + d;
    float x1 = (float)qkv[base], x2 = (float)qkv[base + 64];
    const float sc = 0.12751744737079736f;  // log2(e)/sqrt(128)
    float o1 = (x1 * c - x2 * sn) * sc;
    float o2 = (x2 * c + x1 * sn) * sc;
    size_t ob = ((size_t)((b * 32 + hh) * 2048 + s)) * 128 + d;
    q_r[ob] = (_Float16)o1;
    q_r[ob + 64] = (_Float16)o2;
  } else {
    int hk = hh - 32;
    size_t base = mrow + 4096 + hk * 128 + d;
    float x1 = (float)qkv[base], x2 = (float)qkv[base + 64];
    float o1 = x1 * c - x2 * sn;
    float o2 = x2 * c + x1 * sn;
    size_t ob = ((size_t)((b * 8 + hk) * 2048 + s)) * 128 + d;
    k_r[ob] = (_Float16)o1;
    k_r[ob + 64] = (_Float16)o2;
  }
}

// ---------------- V transpose: qkv v-part -> v_t[b][hv][d][s] ----------------
__global__ void v_transpose(const _Float16* __restrict__ qkv, _Float16* __restrict__ v_t) {
  __shared__ _Float16 tile[32][33];
  int st = blockIdx.x * 32, dt = blockIdx.y * 32, bh = blockIdx.z;
  int tx = threadIdx.x & 31, ty = threadIdx.x >> 5;
  int b = bh >> 3, hv = bh & 7;
#pragma unroll
  for (int j = 0; j < 4; ++j) {
    int s = st + ty + j * 8;
    tile[ty + j * 8][tx] = qkv[(size_t)(b * 2048 + s) * 6144 + 5120 + hv * 128 + dt + tx];
  }
  __syncthreads();
#pragma unroll
  for (int j = 0; j < 4; ++j)
    v_t[((size_t)bh * 128 + dt + ty + j * 8) * 2048 + st + tx] = tile[tx][ty + j * 8];
}

// ---------------- Flash attention: S^T form, 32x32x16 MFMA (unchanged from R4) ----------------
__global__ __launch_bounds__(256, 2) void attn_kernel(const _Float16* __restrict__ q_r,
                                                      const _Float16* __restrict__ k_r,
                                                      const _Float16* __restrict__ v_t,
                                                      _Float16* __restrict__ att) {
  __shared__ __align__(16) _Float16 kt[128 * 128];  // K tile [kv][d]; later P^T [q][kv]
  __shared__ __align__(16) _Float16 vt[128 * 128];  // V^T tile [d][kv]
  const int tid = threadIdx.x;
  const int w = tid >> 6, lane = tid & 63;
  const int l32 = lane & 31, hi = lane >> 5;
  const int qb = 15 - blockIdx.x;  // heavy q-tiles dispatch first
  const int h = blockIdx.y, b = blockIdx.z;
  const int q0 = qb * 128;
  const _Float16* qh = q_r + ((size_t)(b * 32 + h) * 2048) * 128;
  const _Float16* kh = k_r + ((size_t)(b * 8 + (h >> 2)) * 2048) * 128;
  const _Float16* vh = v_t + ((size_t)(b * 8 + (h >> 2)) * 128) * 2048;

  const int ql = w * 32 + l32;
  const int myq = q0 + ql;
  const int swq = SWZ(ql);
  const int swl = SWZ(l32);

  half8 bq[8];
#pragma unroll
  for (int kd = 0; kd < 8; ++kd)
    bq[kd] = *(const half8*)&qh[(size_t)myq * 128 + kd * 16 + hi * 8];

  floatx16 oacc[4];
#pragma unroll
  for (int di = 0; di < 4; ++di)
#pragma unroll
    for (int j = 0; j < 16; ++j) oacc[di][j] = 0.f;
  float mrun = -1e30f, lrun = 0.f;

  const int srow0 = tid >> 4, sgrp = tid & 15;

  for (int kti = 0; kti <= qb; ++kti) {
    __syncthreads();
    const _Float16* kg = kh + (size_t)kti * 128 * 128;
#pragma unroll
    for (int c = 0; c < 8; ++c) {
      int row = srow0 + c * 16;
      int gc = (sgrp ^ SWZ(row)) * 8;
      gld16(kg + row * 128 + gc, &kt[w * 512 + c * 2048]);
    }
#pragma unroll
    for (int c = 0; c < 8; ++c) {
      int row = srow0 + c * 16;
      int gc = (sgrp ^ SWZ(row)) * 8;
      gld16(vh + (size_t)row * 2048 + kti * 128 + gc, &vt[w * 512 + c * 2048]);
    }
    __syncthreads();

    floatx16 sacc[4];
#pragma unroll
    for (int ni = 0; ni < 4; ++ni)
#pragma unroll
      for (int j = 0; j < 16; ++j) sacc[ni][j] = 0.f;
#pragma unroll
    for (int ni = 0; ni < 4; ++ni) {
      int rb = (ni * 32 + l32) * 128;
#pragma unroll
      for (int kd = 0; kd < 8; ++kd) {
        half8 ka = *(const half8*)&kt[rb + (((kd * 2 + hi) ^ swl) * 8)];
        sacc[ni] = __builtin_amdgcn_mfma_f32_32x32x16_f16(ka, bq[kd], sacc[ni], 0, 0, 0);
      }
    }

    if (kti == qb) {
#pragma unroll
      for (int ni = 0; ni < 4; ++ni)
#pragma unroll
        for (int g = 0; g < 4; ++g) {
          int kvb = kti * 128 + ni * 32 + g * 8 + hi * 4;
#pragma unroll
          for (int t = 0; t < 4; ++t)
            if (kvb + t > myq) sacc[ni][g * 4 + t] = -1e30f;
        }
    }

    float tm = -1e30f;
#pragma unroll
    for (int ni = 0; ni < 4; ++ni)
#pragma unroll
      for (int j = 0; j < 16; ++j) tm = fmaxf(tm, sacc[ni][j]);
    tm = fmaxf(tm, __shfl_xor(tm, 32));
    float nm = fmaxf(mrun, tm);
    float al = exp2f(mrun - nm);
    mrun = nm;
    float ts = 0.f;
#pragma unroll
    for (int ni = 0; ni < 4; ++ni)
#pragma unroll
      for (int j = 0; j < 16; ++j) {
        float p = exp2f(sacc[ni][j] - nm);
        sacc[ni][j] = p;
        ts += p;
      }
    ts += __shfl_xor(ts, 32);
    lrun = lrun * al + ts;
#pragma unroll
    for (int di = 0; di < 4; ++di)
#pragma unroll
      for (int j = 0; j < 16; ++j) oacc[di][j] *= al;

    __syncthreads();

#pragma unroll
    for (int ni = 0; ni < 4; ++ni)
#pragma unroll
      for (int g = 0; g < 4; ++g) {
        half4 p4;
#pragma unroll
        for (int t = 0; t < 4; ++t) p4[t] = (_Float16)sacc[ni][g * 4 + t];
        *(half4*)&kt[ql * 128 + (((ni * 4 + g) ^ swq) * 8) + hi * 4] = p4;
      }

#pragma unroll
    for (int ks = 0; ks < 8; ++ks) {
      half8 pb = *(const half8*)&kt[ql * 128 + (((ks * 2 + hi) ^ swq) * 8)];
#pragma unroll
      for (int di = 0; di < 4; ++di) {
        int rv = (di * 32 + l32) * 128;
        half8 va = *(const half8*)&vt[rv + (((ks * 2 + hi) ^ swl) * 8)];
        oacc[di] = __builtin_amdgcn_mfma_f32_32x32x16_f16(va, pb, oacc[di], 0, 0, 0);
      }
    }
  }

  float inv = 1.f / lrun;
  _Float16* ob = att + ((size_t)b * 2048 + myq) * 4096 + h * 128;
#pragma unroll
  for (int di = 0; di < 4; ++di)
#pragma unroll
    for (int g = 0; g < 4; ++g) {
      half4 o4;
#pragma unroll
      for (int t = 0; t < 4; ++t) o4[t] = (_Float16)(oacc[di][g * 4 + t] * inv);
      *(half4*)&ob[di * 32 + g * 8 + hi * 4] = o4;
    }
}

extern "C" void kernel_launch(void* const* d_in, const int* in_sizes, int n_in, void* d_out,
                              int out_size, void* d_ws, size_t ws_size, hipStream_t stream) {
  const float* x = (const float*)d_in[0];
  const float* cosb = (const float*)d_in[1];
  const float* sinb = (const float*)d_in[2];
  const float* Wq = (const float*)d_in[3];
  const float* bq = (const float*)d_in[4];
  const float* Wk = (const float*)d_in[5];
  const float* bk = (const float*)d_in[6];
  const float* Wv = (const float*)d_in[7];
  const float* bv = (const float*)d_in[8];
  const float* Wo = (const float*)d_in[9];
  float* out = (float*)d_out;

  char* p = (char*)d_ws;
  _Float16* xb = (_Float16*)p;   p += (size_t)4096 * 4096 * 2;
  _Float16* wqkv = (_Float16*)p; p += (size_t)6144 * 4096 * 2;
  _Float16* wo_b = (_Float16*)p; p += (size_t)4096 * 4096 * 2;
  _Float16* qkv = (_Float16*)p;  p += (size_t)4096 * 6144 * 2;
  _Float16* q_r = (_Float16*)p;  p += (size_t)2 * 32 * 2048 * 128 * 2;
  _Float16* k_r = (_Float16*)p;  p += (size_t)2 * 8 * 2048 * 128 * 2;
  _Float16* v_t = (_Float16*)p;  p += (size_t)2 * 8 * 128 * 2048 * 2;
  _Float16* att = (_Float16*)p;  p += (size_t)4096 * 4096 * 2;
  float* biasc = (float*)p;      p += 6144 * 4;

  // 7,340,032 convert groups + 24 bias blocks
  convert_all<<<28696, 256, 0, stream>>>(x, Wq, Wk, Wv, Wo, bq, bk, bv, xb, wqkv, wo_b, biasc);

  gemm_bt<_Float16, true><<<dim3(48, 32), 256, 0, stream>>>(xb, wqkv, biasc, qkv, 4096, 6144, 4096);
  rope_qk<<<40960, 256, 0, stream>>>(qkv, cosb, sinb, q_r, k_r);
  v_transpose<<<dim3(64, 4, 16), 256, 0, stream>>>(qkv, v_t);
  attn_kernel<<<dim3(16, 32, 2), 256, 0, stream>>>(q_r, k_r, v_t, att);
  gemm_bt<float, false><<<dim3(32, 32), 256, 0, stream>>>(att, wo_b, nullptr, out, 4096, 4096, 4096);
}